// Round 1
// 292.819 us; speedup vs baseline: 1.0069x; 1.0069x over previous
//
#include <hip/hip_runtime.h>

// Problem constants
#define B_  8
#define C_  64
#define O_  64
#define H_  80
#define W_  800
#define NCHT   13           // transpose kernel: ceil(800/64) 64-px tiles
#define NCHM   25           // main kernel: 800/32 exact 32-px chunks
#define XT_BYTES 65536000u  // 8*80*800*64*2

#define ROWS_ 8             // staged halo rows: h0-3 .. h0+4
#define ROWB_ 5120          // 40 px * 128 B per staged row (cols w0-3..w0+36)
#define LDSX_BYTES (ROWS_ * ROWB_ + 1024)   // 41984 B -> 3 blocks/CU

typedef short bf16x8 __attribute__((ext_vector_type(8)));
typedef float f32x4  __attribute__((ext_vector_type(4)));

__device__ __forceinline__ unsigned short f2bf(float f) {
    unsigned int u = __float_as_uint(f);
    unsigned int r = u + 0x7FFFu + ((u >> 16) & 1u);   // RNE
    return (unsigned short)(r >> 16);
}

__device__ __forceinline__ void gld_lds16(const void* g, void* l) {
    __builtin_amdgcn_global_load_lds(
        (const __attribute__((address_space(1))) unsigned int*)g,
        (__attribute__((address_space(3))) unsigned int*)l, 16, 0, 0);
}

// ---------------------------------------------------------------------------
// Kernel 1: x (B,C,H,W) fp32 -> xT bf16, pixel-major with SWIZZLED channel
// groups: 16-B group g (8 ch) of pixel w stored at position (g + w) & 7.
// The swizzle makes k_main's LDS stride-128 ds_read_b128 bank-conflict-free.
// ---------------------------------------------------------------------------
__global__ void k_transpose(const float* __restrict__ x, unsigned short* __restrict__ xT) {
    __shared__ float tile[64][68];
    const int chunk = blockIdx.x, h = blockIdx.y, b = blockIdx.z;
    const int w0 = chunk * 64;
    const int tid = threadIdx.x;

    const int wf4 = tid & 15;
    const int c0  = tid >> 4;
    const int w   = w0 + wf4 * 4;       // W%4==0: float4 all-valid or all-invalid
#pragma unroll
    for (int it = 0; it < 4; ++it) {
        const int c = it * 16 + c0;
        f32x4 v = {0.f, 0.f, 0.f, 0.f};
        if (w < W_) v = *(const f32x4*)(x + (((b * C_ + c) * H_ + h) * W_) + w);
        *(f32x4*)&tile[c][wf4 * 4] = v;
    }
    __syncthreads();

    const int px = tid >> 2, q = tid & 3;
    const int wabs = w0 + px;
    if (wabs < W_) {
        unsigned int u[8];
#pragma unroll
        for (int i = 0; i < 8; ++i) {
            const int c = q * 16 + 2 * i;
            u[i] = (unsigned int)f2bf(tile[c][px])
                 | ((unsigned int)f2bf(tile[c + 1][px]) << 16);
        }
        unsigned int* base = (unsigned int*)xT + ((size_t)((b * H_ + h) * W_) + wabs) * 32;
        const int g0 = (2 * q + wabs) & 7;
        const int g1 = (2 * q + 1 + wabs) & 7;
        *(uint4*)(base + g0 * 4) = make_uint4(u[0], u[1], u[2], u[3]);
        *(uint4*)(base + g1 * 4) = make_uint4(u[4], u[5], u[6], u[7]);
    }
}

// ---------------------------------------------------------------------------
// Kernel 2: pre-swizzle weight (9,O,C) fp32 into exact A-fragment order, bf16.
// ---------------------------------------------------------------------------
__global__ void k_wfrag(const float* __restrict__ wt, unsigned short* __restrict__ wf) {
    const int t = blockIdx.x * 256 + threadIdx.x;   // < 36864
    const int j    = t & 7;
    const int lane = (t >> 3) & 63;
    const int mt   = (t >> 9) & 3;
    const int ks   = t >> 11;                       // 0..17
    const int tap  = ks >> 1, hf = ks & 1;
    const int o = mt * 16 + (lane & 15);
    const int c = hf * 32 + (lane >> 4) * 8 + j;
    wf[t] = f2bf(wt[(tap * 64 + o) * 64 + c]);
}

// ---------------------------------------------------------------------------
// Kernel 3: gather-GEMM with LDS-staged halo. 32-px chunks (NCHM=25, exact).
// Block = 256 thr = 4 waves over (2 h rows) x (2 o-halves); covers 32-px chunk.
// Stage rows h0-3..h0+4, cols w0-3..w0+36 (41 KB) via global_load_lds x10
// (pure streaming copies -> latency-insensitive); the data-dependent 9-tap
// gather then runs out of LDS as swizzled conflict-free ds_read_b128.
// 41.98 KB LDS -> 3 blocks/CU (12 waves/CU, was 8): stage/compute phases
// of 3 resident blocks overlap, hiding A-load and stage-drain latency.
// ---------------------------------------------------------------------------
__global__ void __launch_bounds__(256, 3)
k_main(const unsigned short* __restrict__ xT,
       const unsigned short* __restrict__ wfrag,
       const float* __restrict__ dh, const float* __restrict__ dw,
       const float* __restrict__ bias, float* __restrict__ out) {
    __shared__ char lx[LDSX_BYTES];
    const int tid  = threadIdx.x;
    const int wave = tid >> 6, lane = tid & 63;

    const unsigned int flat = blockIdx.x;           // 0..7999
    const int b = flat & 7;                         // XCD swizzle: batch per XCD
    const unsigned int l = flat >> 3;               // 0..999
    const int chunk = l % NCHM;
    const int hp    = l / NCHM;                     // 0..39
    const int h0 = hp * 2;
    const int w0 = chunk * 32;
    const int h   = h0 + (wave & 1);
    const int mtb = (wave >> 1) * 2;                // o-half: mt in {mtb, mtb+1}
    const int l15 = lane & 15, kq = lane >> 4;

    // ---- Stage halo: wave stages row-slots 2*wave, 2*wave+1 ----
    {
        const int col0  = (w0 - 3) < 0 ? 0 : (w0 - 3);
        const int shift = (col0 - (w0 - 3)) * 128;  // 0 or 384 (chunk 0)
#pragma unroll
        for (int k = 0; k < 2; ++k) {
            const int slot = wave * 2 + k;
            int ar = h0 - 3 + slot;
            ar = ar < 0 ? 0 : (ar > H_ - 1 ? H_ - 1 : ar);
            const char* src = (const char*)xT
                + ((size_t)(b * H_ + ar) * W_ + col0) * 128;
            char* dst = lx + slot * ROWB_ + shift;
#pragma unroll
            for (int i = 0; i < 5; ++i)
                gld_lds16(src + i * 1024 + lane * 16, dst + i * 1024);
        }
    }

    // ---- Per-pixel gather addresses (LDS byte offsets) ----
    // 25*32 == 800 exactly: pw < W_ always, no clamps needed.
    unsigned int rowb[2][3], colb[2][3];
#pragma unroll
    for (int nt = 0; nt < 2; ++nt) {
        const int pw  = w0 + nt * 16 + l15;
        const int dhi = (int)dh[b * W_ + pw];
        const int dwi = (int)dw[b * W_ + pw];
        int rD = h - dhi;   if (rD < 0) rD = -rD;
        const int rU = (h + dhi < H_) ? (h + dhi) : h;
        int cL = pw - dwi;  if (cL < 0) cL = -cL;
        const int cR = (pw + dwi < W_) ? (pw + dwi) : (2 * W_ - 1 - pw - dwi);
        rowb[nt][0] = (unsigned int)(rD - h0 + 3) * ROWB_;
        rowb[nt][1] = (unsigned int)(h  - h0 + 3) * ROWB_;
        rowb[nt][2] = (unsigned int)(rU - h0 + 3) * ROWB_;
        const int cs[3] = {cL, pw, cR};
#pragma unroll
        for (int j = 0; j < 3; ++j)
            colb[nt][j] = (unsigned int)(cs[j] - (w0 - 3)) * 128u
                        + (unsigned int)(((cs[j] + kq) & 7) * 16);
    }

    const char* wfb = (const char*)wfrag;
    const unsigned int aoff = (unsigned int)lane * 16u;

    // acc init = bias
    f32x4 acc[2][2];
#pragma unroll
    for (int mtl = 0; mtl < 2; ++mtl) {
        const f32x4 bv = *(const f32x4*)(bias + (mtb + mtl) * 16 + kq * 4);
#pragma unroll
        for (int nt = 0; nt < 2; ++nt)
#pragma unroll
            for (int r = 0; r < 4; ++r) acc[mtl][nt][r] = bv[r];
    }

    __syncthreads();   // staging complete (compiler drains vmcnt here)

    // ---- K loop: 18 steps; B dist-1 (LDS), A dist-2 (global) prefetch ----
    bf16x8 bcur[2], bnxt[2], a0[2], a1[2], a2[2];
#pragma unroll
    for (int nt = 0; nt < 2; ++nt)
        bcur[nt] = *(const bf16x8*)(lx + rowb[nt][0] + colb[nt][0]);
#pragma unroll
    for (int mtl = 0; mtl < 2; ++mtl) {
        a0[mtl] = *(const bf16x8*)(wfb + (unsigned int)((0 * 4 + mtb + mtl) * 1024) + aoff);
        a1[mtl] = *(const bf16x8*)(wfb + (unsigned int)((1 * 4 + mtb + mtl) * 1024) + aoff);
    }

#pragma unroll
    for (int s = 0; s < 18; ++s) {
        if (s < 17) {
            const int sn = s + 1;
            const int tap = sn >> 1, hf = sn & 1;
            const int i = tap / 3, j = tap % 3;
#pragma unroll
            for (int nt = 0; nt < 2; ++nt) {
                unsigned int a = rowb[nt][i] + colb[nt][j];
                if (hf) a ^= 64u;                  // ch-group +4 under swizzle
                bnxt[nt] = *(const bf16x8*)(lx + a);
            }
        }
        if (s < 16) {
#pragma unroll
            for (int mtl = 0; mtl < 2; ++mtl)
                a2[mtl] = *(const bf16x8*)(wfb
                            + (unsigned int)(((s + 2) * 4 + mtb + mtl) * 1024) + aoff);
        }
#pragma unroll
        for (int mtl = 0; mtl < 2; ++mtl)
#pragma unroll
            for (int nt = 0; nt < 2; ++nt)
                acc[mtl][nt] = __builtin_amdgcn_mfma_f32_16x16x32_bf16(
                    a0[mtl], bcur[nt], acc[mtl][nt], 0, 0, 0);
#pragma unroll
        for (int nt = 0; nt < 2; ++nt) bcur[nt] = bnxt[nt];
#pragma unroll
        for (int mtl = 0; mtl < 2; ++mtl) { a0[mtl] = a1[mtl]; a1[mtl] = a2[mtl]; }
    }

    // ---- Epilogue: out[b][o][h][w] (w always < W_: exact chunking) ----
#pragma unroll
    for (int mtl = 0; mtl < 2; ++mtl) {
#pragma unroll
        for (int nt = 0; nt < 2; ++nt) {
            const int w = w0 + nt * 16 + l15;
            const unsigned int ob =
                ((unsigned int)(b * O_ + (mtb + mtl) * 16 + kq * 4) * (unsigned int)H_
                 + (unsigned int)h) * (unsigned int)W_ + (unsigned int)w;
#pragma unroll
            for (int r = 0; r < 4; ++r)
                out[ob + (unsigned int)r * 64000u] = acc[mtl][nt][r];
        }
    }
}

extern "C" void kernel_launch(void* const* d_in, const int* in_sizes, int n_in,
                              void* d_out, int out_size, void* d_ws, size_t ws_size,
                              hipStream_t stream) {
    const float* x      = (const float*)d_in[0];   // (8,64,80,800)
    const float* dh     = (const float*)d_in[1];   // (8,1,800)
    const float* dw     = (const float*)d_in[2];   // (8,1,800)
    const float* weight = (const float*)d_in[3];   // (9,64,64)
    const float* bias   = (const float*)d_in[4];   // (64,)
    float* out = (float*)d_out;

    unsigned short* xT    = (unsigned short*)d_ws;
    unsigned short* wfrag = (unsigned short*)((char*)d_ws + XT_BYTES);

    k_transpose<<<dim3(NCHT, H_, B_), 256, 0, stream>>>(x, xT);
    k_wfrag<<<dim3(144), 256, 0, stream>>>(weight, wfrag);
    k_main<<<dim3(NCHM * (H_ / 2) * B_), 256, 0, stream>>>(xT, wfrag, dh, dw, bias, out);
}